// Round 2
// baseline (33318.878 us; speedup 1.0000x reference)
//
#include <hip/hip_runtime.h>
#include <hip/hip_cooperative_groups.h>
#include <cstdint>
#include <cstddef>

namespace cg = cooperative_groups;

// Problem constants
#define B   16
#define SEQ 512
#define HD  768
#define G4  3072   // 4*HD
#define NL  25

using u16 = unsigned short;
using u32 = uint32_t;

__device__ __forceinline__ float bf2f(u16 u){
  union { float f; u32 i; } v; v.i = ((u32)u) << 16; return v.f;
}
__device__ __forceinline__ u16 f2bf(float f){
  union { float f; u32 i; } v; v.f = f;
  u32 r = v.i + 0x7FFFu + ((v.i >> 16) & 1u);  // RNE
  return (u16)(r >> 16);
}
__device__ __forceinline__ float asf(u32 u){ union { float f; u32 i; } v; v.i = u; return v.f; }
__device__ __forceinline__ float sigm(float x){ return 1.f/(1.f + __expf(-x)); }
__device__ __forceinline__ float tanhfast(float x){ return 1.f - 2.f/(__expf(2.f*x) + 1.f); }

struct __align__(8) us4 { u16 x, y, z, w; };
__device__ __forceinline__ float4 ld4(const float* p){ return *(const float4*)p; }
__device__ __forceinline__ float4 ld4(const u16* p){
  us4 v = *(const us4*)p;
  return make_float4(bf2f(v.x), bf2f(v.y), bf2f(v.z), bf2f(v.w));
}

// ---------------------------------------------------------------------------
// prep: WT2[lid][jslot][k][jj] packed-bf16-pair layout for the scan kernel,
//       bias[lid][g] = b_ih + b_hh
// j_local = g*8 + jh_l (0..31); u32 jj holds j_local {2jj, 2jj+1};
// j_glob = g*768 + jslot*8 + jh_l
// ---------------------------------------------------------------------------
struct WPtrs { const float* w[4]; const float* bi[4]; const float* bh[4]; };

__global__ void prep_kernel(WPtrs p, u32* __restrict__ WT2, float* __restrict__ bias){
  const int TOT = 4*96*768*16;
  for (int idx = blockIdx.x*blockDim.x + threadIdx.x; idx < TOT; idx += gridDim.x*blockDim.x){
    int jj  = idx & 15;
    int k   = (idx >> 4) % 768;
    int js  = ((idx >> 4) / 768) % 96;
    int lid = idx / (16*768*96);
    int jlo = 2*jj, jhi = 2*jj + 1;
    int jglo = (jlo >> 3)*768 + js*8 + (jlo & 7);
    int jghi = (jhi >> 3)*768 + js*8 + (jhi & 7);
    u16 lo = f2bf(p.w[lid][(size_t)jglo*HD + k]);
    u16 hi = f2bf(p.w[lid][(size_t)jghi*HD + k]);
    WT2[idx] = (u32)lo | ((u32)hi << 16);
  }
  for (int idx = blockIdx.x*blockDim.x + threadIdx.x; idx < 4*G4; idx += gridDim.x*blockDim.x){
    int lid = idx / G4, g = idx % G4;
    bias[idx] = p.bi[lid][g] + p.bh[lid][g];
  }
}

// ---------------------------------------------------------------------------
// xg GEMM: out[m][n] = bf16( sum_k A[m][k]*W[n][k] + bias[n] )
// M=8192, N=3072, K in {768,1536}. 128x128 tile, 8x8/thread. (unchanged)
// ---------------------------------------------------------------------------
template<typename AT>
__global__ __launch_bounds__(256) void gemm_xg(const AT* __restrict__ A, int K,
    const float* __restrict__ W, const float* __restrict__ bias,
    u16* __restrict__ out)
{
  __shared__ float As[8][128];
  __shared__ float Ws[8][128];
  const int tid = threadIdx.x;
  const int bm = blockIdx.y * 128;
  const int bn = blockIdx.x * 128;
  const int tx = tid & 15, ty = tid >> 4;
  const int lr = tid >> 1;
  const int lc = (tid & 1) * 4;
  float acc[8][8] = {};
  for (int k0 = 0; k0 < K; k0 += 8){
    {
      float4 av = ld4(A + (size_t)(bm + lr)*K + (k0 + lc));
      As[lc+0][lr]=av.x; As[lc+1][lr]=av.y; As[lc+2][lr]=av.z; As[lc+3][lr]=av.w;
      float4 wv = *(const float4*)(W + (size_t)(bn + lr)*K + (k0 + lc));
      Ws[lc+0][lr]=wv.x; Ws[lc+1][lr]=wv.y; Ws[lc+2][lr]=wv.z; Ws[lc+3][lr]=wv.w;
    }
    __syncthreads();
    #pragma unroll
    for (int kk = 0; kk < 8; kk++){
      float a[8], bb[8];
      *(float4*)&a[0]  = *(const float4*)&As[kk][ty*8];
      *(float4*)&a[4]  = *(const float4*)&As[kk][ty*8+4];
      *(float4*)&bb[0] = *(const float4*)&Ws[kk][tx*4];
      *(float4*)&bb[4] = *(const float4*)&Ws[kk][64 + tx*4];
      #pragma unroll
      for (int i = 0; i < 8; i++)
        #pragma unroll
        for (int j = 0; j < 8; j++)
          acc[i][j] = fmaf(a[i], bb[j], acc[i][j]);
    }
    __syncthreads();
  }
  float bv[8];
  *(float4*)&bv[0] = *(const float4*)&bias[bn + tx*4];
  *(float4*)&bv[4] = *(const float4*)&bias[bn + 64 + tx*4];
  #pragma unroll
  for (int i = 0; i < 8; i++){
    size_t row = bm + ty*8 + i;
    u16 o0[4], o1[4];
    #pragma unroll
    for (int j = 0; j < 4; j++){
      o0[j] = f2bf(acc[i][j]   + bv[j]);
      o1[j] = f2bf(acc[i][4+j] + bv[4+j]);
    }
    uint2 p0; p0.x = (u32)o0[0] | ((u32)o0[1]<<16); p0.y = (u32)o0[2] | ((u32)o0[3]<<16);
    uint2 p1; p1.x = (u32)o1[0] | ((u32)o1[1]<<16); p1.y = (u32)o1[2] | ((u32)o1[3]<<16);
    *(uint2*)(out + row*G4 + bn + tx*4)      = p0;
    *(uint2*)(out + row*G4 + bn + 64 + tx*4) = p1;
  }
}

// ---------------------------------------------------------------------------
// Persistent cooperative LSTM scan (one layer, both dirs).
// 192 blocks x 256 thr. Block: dir = bid/96, jslot = bid%96 (8 h-units).
// Per step: stage h (48KB) -> 8jx4bx48k FMA tiles -> shfl+LDS ks-reduce ->
// gates (c in LDS) -> write h slice to ping-pong global -> grid.sync().
// LAYER0 stores h as bf16 into hout; LAYER1 stores tanh(h).
// ---------------------------------------------------------------------------
template<int LAYER>
__global__ __launch_bounds__(256, 1) void scan_kernel(
    const u16* __restrict__ xg,      // [dir][b*SEQ+t][G4]
    const u32* __restrict__ WT2,     // [dir][96][768][16] (this layer's slice)
    float* __restrict__ hg,          // [2 ping][2 dir][768][16]
    u16* __restrict__ hout)          // [b*SEQ+t][1536]
{
  __shared__ u32  Wl[768*16];     // 48 KB packed bf16 pairs, [k][jj]
  __shared__ float hL[768*16];    // 48 KB, [k][b]
  __shared__ float red2[512*4];   // 8 KB, [out][wave]
  __shared__ float cL[128];       // c state [jh_l][b]

  cg::grid_group grid = cg::this_grid();
  const int tid = threadIdx.x;
  const int dir = blockIdx.x / 96;
  const int js  = blockIdx.x % 96;

  { // stage W once (49152 B contiguous)
    const uint4* src = (const uint4*)(WT2 + (size_t)(dir*96 + js)*768*16);
    uint4* dst = (uint4*)Wl;
    #pragma unroll
    for (int i = 0; i < 12; i++) dst[i*256 + tid] = src[i*256 + tid];
  }
  if (tid < 128) cL[tid] = 0.f;
  __syncthreads();

  const int jg = tid & 3;            // gate index (owns 8 j of that gate)
  const int bg = (tid >> 2) & 3;     // batch quad
  const int ks = tid >> 4;           // k-slice 0..15 (k = ks + 16*i)
  const int jh_l = tid >> 4;         // gate-phase mapping (tid<128)
  const int b_g  = tid & 15;

  for (int s = 0; s < SEQ; s++){
    const int t_seq = dir ? (SEQ-1-s) : s;

    // early xg loads for gate phase (hide global latency under compute)
    float xgv[4];
    if (tid < 128){
      const u16* xp = xg + (((size_t)(dir*B + b_g))*SEQ + t_seq)*G4 + js*8 + jh_l;
      #pragma unroll
      for (int g = 0; g < 4; g++) xgv[g] = bf2f(xp[g*HD]);
    }

    // stage h(t-1): 48 KB global -> LDS
    {
      const float4* src = (const float4*)(hg + (size_t)((s&1)*2 + dir)*(768*16));
      float4 tmp[12];
      #pragma unroll
      for (int i = 0; i < 12; i++) tmp[i] = src[i*256 + tid];
      #pragma unroll
      for (int i = 0; i < 12; i++) ((float4*)hL)[i*256 + tid] = tmp[i];
    }
    __syncthreads();

    // compute: acc[j 8][b 4] over 48 k values (k = ks + 16*i)
    float acc[8][4];
    #pragma unroll
    for (int a = 0; a < 8; a++)
      #pragma unroll
      for (int b2 = 0; b2 < 4; b2++) acc[a][b2] = 0.f;

    #pragma unroll 4
    for (int i = 0; i < 48; i++){
      const int k = ks + (i << 4);
      uint4 wv  = *(const uint4*)&Wl[k*16 + jg*4];
      float4 hv = *(const float4*)&hL[k*16 + bg*4];
      float wj[8];
      wj[0]=asf(wv.x<<16); wj[1]=asf(wv.x&0xffff0000u);
      wj[2]=asf(wv.y<<16); wj[3]=asf(wv.y&0xffff0000u);
      wj[4]=asf(wv.z<<16); wj[5]=asf(wv.z&0xffff0000u);
      wj[6]=asf(wv.w<<16); wj[7]=asf(wv.w&0xffff0000u);
      const float hb[4] = {hv.x, hv.y, hv.z, hv.w};
      #pragma unroll
      for (int a = 0; a < 8; a++)
        #pragma unroll
        for (int b2 = 0; b2 < 4; b2++)
          acc[a][b2] = fmaf(wj[a], hb[b2], acc[a][b2]);
    }

    // ks-reduce: 4-way within wave via shfl, 4 waves via LDS
    const int wv_id = tid >> 6;
    #pragma unroll
    for (int a = 0; a < 8; a++)
      #pragma unroll
      for (int b2 = 0; b2 < 4; b2++){
        float v = acc[a][b2];
        v += __shfl_xor(v, 16);
        v += __shfl_xor(v, 32);
        if ((tid & 48) == 0){
          int out = (jg*8 + a)*16 + bg*4 + b2;
          red2[out*4 + wv_id] = v;
        }
      }
    __syncthreads();

    // gates + state update + h writeback
    if (tid < 128){
      float gs[4];
      #pragma unroll
      for (int g = 0; g < 4; g++){
        int out = (g*8 + jh_l)*16 + b_g;
        float4 r = *(const float4*)&red2[out*4];
        gs[g] = r.x + r.y + r.z + r.w + xgv[g];
      }
      float c  = cL[tid];
      float ct = sigm(gs[1])*c + sigm(gs[0])*tanhfast(gs[2]);
      float h  = sigm(gs[3])*tanhfast(ct);
      cL[tid] = ct;
      float* hdst = hg + (size_t)(((s&1)^1)*2 + dir)*(768*16);
      hdst[(js*8 + jh_l)*16 + b_g] = h;
      int jhg = js*8 + jh_l;
      float hw = (LAYER == 0) ? h : tanhfast(h);
      hout[((size_t)b_g*SEQ + t_seq)*1536 + dir*HD + jhg] = f2bf(hw);
    }
    grid.sync();
  }
}

// ---------------------------------------------------------------------------
// logits[row][l] = tanh(h2)[row] . clf_w[l] + clf_b[l]  (th already tanh'd)
// ---------------------------------------------------------------------------
__global__ __launch_bounds__(256) void logits_kernel(const u16* __restrict__ th,
    const float* __restrict__ clf_w, const float* __restrict__ clf_b,
    float* __restrict__ logits)
{
  __shared__ u16 xl[8*1536];
  const int tid = threadIdx.x;
  const int row0 = blockIdx.x * 8;
  {
    const uint4* src = (const uint4*)(th + (size_t)row0*1536);
    uint4* dst = (uint4*)xl;
    #pragma unroll
    for (int i = 0; i < 6; i++) dst[i*256 + tid] = src[i*256 + tid];
  }
  __syncthreads();
  const int r = tid >> 5, l = tid & 31;
  if (l < NL){
    float acc = clf_b[l];
    const float* wr = clf_w + (size_t)l*1536;
    #pragma unroll 2
    for (int kk = 0; kk < 192; kk++){
      uint4 xv = *(const uint4*)&xl[r*1536 + kk*8];
      float4 w0 = *(const float4*)(wr + kk*8);
      float4 w1 = *(const float4*)(wr + kk*8 + 4);
      acc = fmaf(asf(xv.x<<16), w0.x, acc); acc = fmaf(asf(xv.x&0xffff0000u), w0.y, acc);
      acc = fmaf(asf(xv.y<<16), w0.z, acc); acc = fmaf(asf(xv.y&0xffff0000u), w0.w, acc);
      acc = fmaf(asf(xv.z<<16), w1.x, acc); acc = fmaf(asf(xv.z&0xffff0000u), w1.y, acc);
      acc = fmaf(asf(xv.w<<16), w1.z, acc); acc = fmaf(asf(xv.w&0xffff0000u), w1.w, acc);
    }
    logits[(size_t)(row0 + r)*NL + l] = acc;
  }
}

// ---------------------------------------------------------------------------
// CRF numerator + lengths (per b)
// ---------------------------------------------------------------------------
__global__ __launch_bounds__(256) void crf_num(const float* __restrict__ logits,
    const int* __restrict__ targets, const float* __restrict__ trans,
    const float* __restrict__ start, const float* __restrict__ endv,
    float* __restrict__ numlen)
{
  const int b = blockIdx.x;
  const int* tg = targets + (size_t)b*SEQ;
  float s = 0.f; int cnt = 0;
  for (int t = threadIdx.x; t < SEQ; t += 256){
    int cur = tg[t];
    if (cur >= 0){
      cnt++;
      float e = logits[((size_t)b*SEQ + t)*NL + cur];
      s += e;
      if (t > 0) s += trans[tg[t-1]*NL + cur];
    }
  }
  __shared__ float ss[256]; __shared__ int sc[256];
  ss[threadIdx.x] = s; sc[threadIdx.x] = cnt;
  __syncthreads();
  for (int o = 128; o > 0; o >>= 1){
    if (threadIdx.x < o){ ss[threadIdx.x] += ss[threadIdx.x+o]; sc[threadIdx.x] += sc[threadIdx.x+o]; }
    __syncthreads();
  }
  if (threadIdx.x == 0){
    int len = sc[0];
    numlen[b]      = ss[0] + start[tg[0]] + endv[tg[len-1]];
    numlen[16 + b] = (float)len;
  }
}

// ---------------------------------------------------------------------------
// CRF forward algorithm (denominator), one wave per b, lane j = state j
// ---------------------------------------------------------------------------
__global__ __launch_bounds__(64) void crf_fwd(const float* __restrict__ logits,
    const int* __restrict__ targets, const float* __restrict__ trans,
    const float* __restrict__ start, const float* __restrict__ endv,
    float* __restrict__ denom)
{
  const int b = blockIdx.x, lane = threadIdx.x;
  __shared__ float tr[NL*NL];
  for (int i = lane; i < NL*NL; i += 64) tr[i] = trans[i];
  __syncthreads();
  const bool act = lane < NL;
  const int j = act ? lane : 0;
  float alpha = act ? (start[j] + logits[(size_t)b*SEQ*NL + j]) : -3e38f;
  const int* tg = targets + (size_t)b*SEQ;
  for (int t = 1; t < SEQ; t++){
    if (tg[t] < 0) break;
    float e = logits[((size_t)b*SEQ + t)*NL + j];
    float v[NL]; float mx = -3e38f;
    #pragma unroll
    for (int i = 0; i < NL; i++){
      float ai = __shfl(alpha, i);
      v[i] = ai + tr[i*NL + j];
      mx = fmaxf(mx, v[i]);
    }
    float sum = 0.f;
    #pragma unroll
    for (int i = 0; i < NL; i++) sum += __expf(v[i] - mx);
    float nxt = mx + __logf(sum) + e;
    if (act) alpha = nxt;
  }
  float x = act ? alpha + endv[j] : -3e38f;
  float m2 = x;
  #pragma unroll
  for (int off = 32; off >= 1; off >>= 1) m2 = fmaxf(m2, __shfl_xor(m2, off));
  float se = __expf(x - m2);
  #pragma unroll
  for (int off = 32; off >= 1; off >>= 1) se += __shfl_xor(se, off);
  if (lane == 0) denom[b] = m2 + __logf(se);
}

__global__ void crf_final(const float* __restrict__ numlen, const float* __restrict__ denom,
                          float* __restrict__ out)
{
  if (blockIdx.x == 0 && threadIdx.x == 0){
    float sn = 0.f, sl = 0.f;
    for (int b = 0; b < 16; b++){ sn += numlen[b] - denom[b]; sl += numlen[16+b]; }
    out[0] = -sn / sl;
  }
}

// ---------------------------------------------------------------------------
extern "C" void kernel_launch(void* const* d_in, const int* in_sizes, int n_in,
                              void* d_out, int out_size, void* d_ws, size_t ws_size,
                              hipStream_t stream)
{
  const float* hidden  = (const float*)d_in[0];
  const int*   targets = (const int*)  d_in[1];
  const float* w_ih[4] = {(const float*)d_in[2], (const float*)d_in[6], (const float*)d_in[10], (const float*)d_in[14]};
  const float* w_hh[4] = {(const float*)d_in[3], (const float*)d_in[7], (const float*)d_in[11], (const float*)d_in[15]};
  const float* b_ih[4] = {(const float*)d_in[4], (const float*)d_in[8], (const float*)d_in[12], (const float*)d_in[16]};
  const float* b_hh[4] = {(const float*)d_in[5], (const float*)d_in[9], (const float*)d_in[13], (const float*)d_in[17]};
  const float* clf_w = (const float*)d_in[18];
  const float* clf_b = (const float*)d_in[19];
  const float* trans = (const float*)d_in[20];
  const float* start = (const float*)d_in[21];
  const float* endv  = (const float*)d_in[22];

  // workspace layout (~146 MB)
  char* p = (char*)d_ws;
  auto alloc = [&](size_t bytes){ void* r = (void*)p; p += (bytes + 255) & ~(size_t)255; return r; };
  u32*   WT2    = (u32*)  alloc((size_t)4*96*768*16*4);       // 18.9 MB packed W_hh
  float* bias   = (float*)alloc((size_t)4*G4*4);
  u16*   xg     = (u16*)  alloc((size_t)2*B*SEQ*G4*2);        // 100.7 MB
  u16*   h1     = (u16*)  alloc((size_t)B*SEQ*2*HD*2);        // 25.2 MB (doubles as th)
  float* hg     = (float*)alloc((size_t)2*2*768*16*4);        // 192 KB ping-pong h
  float* logits = (float*)alloc((size_t)B*SEQ*NL*4);
  float* numlen = (float*)alloc(32*4);
  float* denom  = (float*)alloc(16*4);
  if ((size_t)(p - (char*)d_ws) > ws_size) return;

  WPtrs wp;
  for (int i = 0; i < 4; i++){ wp.w[i] = w_hh[i]; wp.bi[i] = b_ih[i]; wp.bh[i] = b_hh[i]; }
  prep_kernel<<<4096, 256, 0, stream>>>(wp, WT2, bias);

  const dim3 ggrid(24, 64);
  const size_t xg_dir = (size_t)B*SEQ*G4;
  const size_t wt2_layer = (size_t)2*96*768*16;

  // ---- layer 0 ----
  gemm_xg<float><<<ggrid, 256, 0, stream>>>(hidden, HD, w_ih[0], bias + 0*G4, xg);
  gemm_xg<float><<<ggrid, 256, 0, stream>>>(hidden, HD, w_ih[1], bias + 1*G4, xg + xg_dir);
  hipMemsetAsync(hg, 0, (size_t)2*2*768*16*4, stream);
  {
    const u16* a0 = xg; const u32* a1 = WT2; float* a2 = hg; u16* a3 = h1;
    void* args[] = { &a0, &a1, &a2, &a3 };
    hipLaunchCooperativeKernel(reinterpret_cast<void*>(&scan_kernel<0>),
                               dim3(192), dim3(256), args, 0, stream);
  }

  // ---- layer 1 ----
  gemm_xg<u16><<<ggrid, 256, 0, stream>>>(h1, 2*HD, w_ih[2], bias + 2*G4, xg);
  gemm_xg<u16><<<ggrid, 256, 0, stream>>>(h1, 2*HD, w_ih[3], bias + 3*G4, xg + xg_dir);
  hipMemsetAsync(hg, 0, (size_t)2*2*768*16*4, stream);
  {
    const u16* a0 = xg; const u32* a1 = WT2 + wt2_layer; float* a2 = hg; u16* a3 = h1;
    void* args[] = { &a0, &a1, &a2, &a3 };
    hipLaunchCooperativeKernel(reinterpret_cast<void*>(&scan_kernel<1>),
                               dim3(192), dim3(256), args, 0, stream);
  }

  // ---- classifier + CRF ----
  logits_kernel<<<1024, 256, 0, stream>>>(h1, clf_w, clf_b, logits);
  crf_num<<<16, 256, 0, stream>>>(logits, targets, trans, start, endv, numlen);
  crf_fwd<<<16, 64, 0, stream>>>(logits, targets, trans, start, endv, denom);
  crf_final<<<1, 64, 0, stream>>>(numlen, denom, (float*)d_out);
}

// Round 3
// 11113.779 us; speedup vs baseline: 2.9980x; 2.9980x over previous
//
#include <hip/hip_runtime.h>
#include <cstdint>
#include <cstddef>

// Problem constants
#define B   16
#define SEQ 512
#define HD  768
#define G4  3072   // 4*HD
#define NL  25
#define NBLK 96    // blocks per direction in the scan

using u16 = unsigned short;
using u32 = uint32_t;

__device__ __forceinline__ float bf2f(u16 u){
  union { float f; u32 i; } v; v.i = ((u32)u) << 16; return v.f;
}
__device__ __forceinline__ u16 f2bf(float f){
  union { float f; u32 i; } v; v.f = f;
  u32 r = v.i + 0x7FFFu + ((v.i >> 16) & 1u);  // RNE
  return (u16)(r >> 16);
}
__device__ __forceinline__ float asf(u32 u){ union { float f; u32 i; } v; v.i = u; return v.f; }
__device__ __forceinline__ float sigm(float x){ return 1.f/(1.f + __expf(-x)); }
__device__ __forceinline__ float tanhfast(float x){ return 1.f - 2.f/(__expf(2.f*x) + 1.f); }

struct __align__(8) us4 { u16 x, y, z, w; };
__device__ __forceinline__ float4 ld4(const float* p){ return *(const float4*)p; }
__device__ __forceinline__ float4 ld4(const u16* p){
  us4 v = *(const us4*)p;
  return make_float4(bf2f(v.x), bf2f(v.y), bf2f(v.z), bf2f(v.w));
}

// ---------------------------------------------------------------------------
// prep: WT2[lid][jslot][k][jj] packed-bf16-pair layout for the scan kernel,
//       bias[lid][g] = b_ih + b_hh
// ---------------------------------------------------------------------------
struct WPtrs { const float* w[4]; const float* bi[4]; const float* bh[4]; };

__global__ void prep_kernel(WPtrs p, u32* __restrict__ WT2, float* __restrict__ bias){
  const int TOT = 4*96*768*16;
  for (int idx = blockIdx.x*blockDim.x + threadIdx.x; idx < TOT; idx += gridDim.x*blockDim.x){
    int jj  = idx & 15;
    int k   = (idx >> 4) % 768;
    int js  = ((idx >> 4) / 768) % 96;
    int lid = idx / (16*768*96);
    int jlo = 2*jj, jhi = 2*jj + 1;
    int jglo = (jlo >> 3)*768 + js*8 + (jlo & 7);
    int jghi = (jhi >> 3)*768 + js*8 + (jhi & 7);
    u16 lo = f2bf(p.w[lid][(size_t)jglo*HD + k]);
    u16 hi = f2bf(p.w[lid][(size_t)jghi*HD + k]);
    WT2[idx] = (u32)lo | ((u32)hi << 16);
  }
  for (int idx = blockIdx.x*blockDim.x + threadIdx.x; idx < 4*G4; idx += gridDim.x*blockDim.x){
    int lid = idx / G4, g = idx % G4;
    bias[idx] = p.bi[lid][g] + p.bh[lid][g];
  }
}

// ---------------------------------------------------------------------------
// xg GEMM: out[m][n] = bf16( sum_k A[m][k]*W[n][k] + bias[n] )  (unchanged)
// ---------------------------------------------------------------------------
template<typename AT>
__global__ __launch_bounds__(256) void gemm_xg(const AT* __restrict__ A, int K,
    const float* __restrict__ W, const float* __restrict__ bias,
    u16* __restrict__ out)
{
  __shared__ float As[8][128];
  __shared__ float Ws[8][128];
  const int tid = threadIdx.x;
  const int bm = blockIdx.y * 128;
  const int bn = blockIdx.x * 128;
  const int tx = tid & 15, ty = tid >> 4;
  const int lr = tid >> 1;
  const int lc = (tid & 1) * 4;
  float acc[8][8] = {};
  for (int k0 = 0; k0 < K; k0 += 8){
    {
      float4 av = ld4(A + (size_t)(bm + lr)*K + (k0 + lc));
      As[lc+0][lr]=av.x; As[lc+1][lr]=av.y; As[lc+2][lr]=av.z; As[lc+3][lr]=av.w;
      float4 wv = *(const float4*)(W + (size_t)(bn + lr)*K + (k0 + lc));
      Ws[lc+0][lr]=wv.x; Ws[lc+1][lr]=wv.y; Ws[lc+2][lr]=wv.z; Ws[lc+3][lr]=wv.w;
    }
    __syncthreads();
    #pragma unroll
    for (int kk = 0; kk < 8; kk++){
      float a[8], bb[8];
      *(float4*)&a[0]  = *(const float4*)&As[kk][ty*8];
      *(float4*)&a[4]  = *(const float4*)&As[kk][ty*8+4];
      *(float4*)&bb[0] = *(const float4*)&Ws[kk][tx*4];
      *(float4*)&bb[4] = *(const float4*)&Ws[kk][64 + tx*4];
      #pragma unroll
      for (int i = 0; i < 8; i++)
        #pragma unroll
        for (int j = 0; j < 8; j++)
          acc[i][j] = fmaf(a[i], bb[j], acc[i][j]);
    }
    __syncthreads();
  }
  float bv[8];
  *(float4*)&bv[0] = *(const float4*)&bias[bn + tx*4];
  *(float4*)&bv[4] = *(const float4*)&bias[bn + 64 + tx*4];
  #pragma unroll
  for (int i = 0; i < 8; i++){
    size_t row = bm + ty*8 + i;
    u16 o0[4], o1[4];
    #pragma unroll
    for (int j = 0; j < 4; j++){
      o0[j] = f2bf(acc[i][j]   + bv[j]);
      o1[j] = f2bf(acc[i][4+j] + bv[4+j]);
    }
    uint2 p0; p0.x = (u32)o0[0] | ((u32)o0[1]<<16); p0.y = (u32)o0[2] | ((u32)o0[3]<<16);
    uint2 p1; p1.x = (u32)o1[0] | ((u32)o1[1]<<16); p1.y = (u32)o1[2] | ((u32)o1[3]<<16);
    *(uint2*)(out + row*G4 + bn + tx*4)      = p0;
    *(uint2*)(out + row*G4 + bn + 64 + tx*4) = p1;
  }
}

// ---------------------------------------------------------------------------
// Persistent LSTM scan with hand-rolled relaxed-atomic barrier (per dir).
// 192 blocks x 256 thr. Block: dir = bid/96, js = bid%96 (8 h-units).
// Step: prefetch xg -> poll cnt[dir][s]==96 -> atomic-load H[s] -> FMA tiles
// -> shfl+LDS ks-reduce -> gates -> atomic-store h slice -> syncthreads
// (drains vmcnt) -> leader atomicAdd(cnt[dir][s+1]).
// Max skew between blocks is 1 step => 2-buffer ping-pong is safe.
// ---------------------------------------------------------------------------
template<int LAYER>
__global__ __launch_bounds__(256, 1) void scan_kernel(
    const u16* __restrict__ xg,      // [dir][b*SEQ+t][G4]
    const u32* __restrict__ WT2,     // [dir][96][768][16] (this layer's slice)
    float* __restrict__ hg,          // [2 ping][2 dir][768][16]
    u32*   __restrict__ cnt,         // [2 dir][SEQ+1], zeroed
    u16* __restrict__ hout)          // [b*SEQ+t][1536]
{
  __shared__ u32  Wl[768*16];     // 48 KB packed bf16 pairs, [k][jj]
  __shared__ float hL[768*16];    // 48 KB, [k][b]
  __shared__ float red2[512*4];   // 8 KB
  __shared__ float cL[128];       // c state

  const int tid = threadIdx.x;
  const int dir = blockIdx.x / NBLK;
  const int js  = blockIdx.x % NBLK;

  { // stage W once
    const uint4* src = (const uint4*)(WT2 + (size_t)(dir*NBLK + js)*768*16);
    uint4* dst = (uint4*)Wl;
    #pragma unroll
    for (int i = 0; i < 12; i++) dst[i*256 + tid] = src[i*256 + tid];
  }
  if (tid < 128) cL[tid] = 0.f;
  __syncthreads();

  const int jg = tid & 3;            // gate index
  const int bg = (tid >> 2) & 3;     // batch quad
  const int ks = tid >> 4;           // k-slice 0..15
  const int jh_l = tid >> 4;         // gate-phase j (tid<128)
  const int b_g  = tid & 15;

  u32* mycnt = cnt + dir*(SEQ+1);

  for (int s = 0; s < SEQ; s++){
    const int t_seq = dir ? (SEQ-1-s) : s;

    // xg prefetch BEFORE the barrier poll: latency hides under the wait
    float xgv[4];
    if (tid < 128){
      const u16* xp = xg + (((size_t)(dir*B + b_g))*SEQ + t_seq)*G4 + js*8 + jh_l;
      #pragma unroll
      for (int g = 0; g < 4; g++) xgv[g] = bf2f(xp[g*HD]);
    }

    // wait for all 96 producer blocks of this dir to publish H[s]
    if (s > 0){
      if (tid == 0){
        while (__hip_atomic_load(&mycnt[s], __ATOMIC_RELAXED, __HIP_MEMORY_SCOPE_AGENT) < (u32)NBLK)
          __builtin_amdgcn_s_sleep(1);
      }
      __syncthreads();
    }

    // load H[s] from coherent point -> LDS
    {
      const float* src = hg + (size_t)((s&1)*2 + dir)*(768*16);
      float tmp[48];
      #pragma unroll
      for (int i = 0; i < 48; i++)
        tmp[i] = __hip_atomic_load(&src[i*256 + tid], __ATOMIC_RELAXED, __HIP_MEMORY_SCOPE_AGENT);
      #pragma unroll
      for (int i = 0; i < 48; i++)
        hL[i*256 + tid] = tmp[i];
    }
    __syncthreads();

    // compute: acc[j 8][b 4] over 48 k values (k = ks + 16*i)
    float acc[8][4];
    #pragma unroll
    for (int a = 0; a < 8; a++)
      #pragma unroll
      for (int b2 = 0; b2 < 4; b2++) acc[a][b2] = 0.f;

    #pragma unroll 4
    for (int i = 0; i < 48; i++){
      const int k = ks + (i << 4);
      uint4 wv  = *(const uint4*)&Wl[k*16 + jg*4];
      float4 hv = *(const float4*)&hL[k*16 + bg*4];
      float wj[8];
      wj[0]=asf(wv.x<<16); wj[1]=asf(wv.x&0xffff0000u);
      wj[2]=asf(wv.y<<16); wj[3]=asf(wv.y&0xffff0000u);
      wj[4]=asf(wv.z<<16); wj[5]=asf(wv.z&0xffff0000u);
      wj[6]=asf(wv.w<<16); wj[7]=asf(wv.w&0xffff0000u);
      const float hb[4] = {hv.x, hv.y, hv.z, hv.w};
      #pragma unroll
      for (int a = 0; a < 8; a++)
        #pragma unroll
        for (int b2 = 0; b2 < 4; b2++)
          acc[a][b2] = fmaf(wj[a], hb[b2], acc[a][b2]);
    }

    // ks-reduce: 4-way within wave via shfl, 4 waves via LDS
    const int wv_id = tid >> 6;
    #pragma unroll
    for (int a = 0; a < 8; a++)
      #pragma unroll
      for (int b2 = 0; b2 < 4; b2++){
        float v = acc[a][b2];
        v += __shfl_xor(v, 16);
        v += __shfl_xor(v, 32);
        if ((tid & 48) == 0){
          int out = (jg*8 + a)*16 + bg*4 + b2;
          red2[out*4 + wv_id] = v;
        }
      }
    __syncthreads();

    // gates + state update + h publish
    if (tid < 128){
      float gs[4];
      #pragma unroll
      for (int g = 0; g < 4; g++){
        int out = (g*8 + jh_l)*16 + b_g;
        float4 r = *(const float4*)&red2[out*4];
        gs[g] = r.x + r.y + r.z + r.w + xgv[g];
      }
      float c  = cL[tid];
      float ct = sigm(gs[1])*c + sigm(gs[0])*tanhfast(gs[2]);
      float h  = sigm(gs[3])*tanhfast(ct);
      cL[tid] = ct;
      float* hdst = hg + (size_t)(((s+1)&1)*2 + dir)*(768*16);
      __hip_atomic_store(&hdst[(js*8 + jh_l)*16 + b_g], h,
                         __ATOMIC_RELAXED, __HIP_MEMORY_SCOPE_AGENT);
      int jhg = js*8 + jh_l;
      float hw = (LAYER == 0) ? h : tanhfast(h);
      hout[((size_t)b_g*SEQ + t_seq)*1536 + dir*HD + jhg] = f2bf(hw);
    }
    __syncthreads();   // compiler drains vmcnt(0) before s_barrier -> stores visible
    if (tid == 0)
      __hip_atomic_fetch_add(&mycnt[s+1], 1u, __ATOMIC_RELAXED, __HIP_MEMORY_SCOPE_AGENT);
  }
}

// ---------------------------------------------------------------------------
// logits[row][l] = tanh(h2)[row] . clf_w[l] + clf_b[l]  (th already tanh'd)
// ---------------------------------------------------------------------------
__global__ __launch_bounds__(256) void logits_kernel(const u16* __restrict__ th,
    const float* __restrict__ clf_w, const float* __restrict__ clf_b,
    float* __restrict__ logits)
{
  __shared__ u16 xl[8*1536];
  const int tid = threadIdx.x;
  const int row0 = blockIdx.x * 8;
  {
    const uint4* src = (const uint4*)(th + (size_t)row0*1536);
    uint4* dst = (uint4*)xl;
    #pragma unroll
    for (int i = 0; i < 6; i++) dst[i*256 + tid] = src[i*256 + tid];
  }
  __syncthreads();
  const int r = tid >> 5, l = tid & 31;
  if (l < NL){
    float acc = clf_b[l];
    const float* wr = clf_w + (size_t)l*1536;
    #pragma unroll 2
    for (int kk = 0; kk < 192; kk++){
      uint4 xv = *(const uint4*)&xl[r*1536 + kk*8];
      float4 w0 = *(const float4*)(wr + kk*8);
      float4 w1 = *(const float4*)(wr + kk*8 + 4);
      acc = fmaf(asf(xv.x<<16), w0.x, acc); acc = fmaf(asf(xv.x&0xffff0000u), w0.y, acc);
      acc = fmaf(asf(xv.y<<16), w0.z, acc); acc = fmaf(asf(xv.y&0xffff0000u), w0.w, acc);
      acc = fmaf(asf(xv.z<<16), w1.x, acc); acc = fmaf(asf(xv.z&0xffff0000u), w1.y, acc);
      acc = fmaf(asf(xv.w<<16), w1.z, acc); acc = fmaf(asf(xv.w&0xffff0000u), w1.w, acc);
    }
    logits[(size_t)(row0 + r)*NL + l] = acc;
  }
}

// ---------------------------------------------------------------------------
// CRF numerator + lengths (per b)
// ---------------------------------------------------------------------------
__global__ __launch_bounds__(256) void crf_num(const float* __restrict__ logits,
    const int* __restrict__ targets, const float* __restrict__ trans,
    const float* __restrict__ start, const float* __restrict__ endv,
    float* __restrict__ numlen)
{
  const int b = blockIdx.x;
  const int* tg = targets + (size_t)b*SEQ;
  float s = 0.f; int cnt = 0;
  for (int t = threadIdx.x; t < SEQ; t += 256){
    int cur = tg[t];
    if (cur >= 0){
      cnt++;
      float e = logits[((size_t)b*SEQ + t)*NL + cur];
      s += e;
      if (t > 0) s += trans[tg[t-1]*NL + cur];
    }
  }
  __shared__ float ss[256]; __shared__ int sc[256];
  ss[threadIdx.x] = s; sc[threadIdx.x] = cnt;
  __syncthreads();
  for (int o = 128; o > 0; o >>= 1){
    if (threadIdx.x < o){ ss[threadIdx.x] += ss[threadIdx.x+o]; sc[threadIdx.x] += sc[threadIdx.x+o]; }
    __syncthreads();
  }
  if (threadIdx.x == 0){
    int len = sc[0];
    numlen[b]      = ss[0] + start[tg[0]] + endv[tg[len-1]];
    numlen[16 + b] = (float)len;
  }
}

// ---------------------------------------------------------------------------
// CRF forward algorithm (denominator), one wave per b
// ---------------------------------------------------------------------------
__global__ __launch_bounds__(64) void crf_fwd(const float* __restrict__ logits,
    const int* __restrict__ targets, const float* __restrict__ trans,
    const float* __restrict__ start, const float* __restrict__ endv,
    float* __restrict__ denom)
{
  const int b = blockIdx.x, lane = threadIdx.x;
  __shared__ float tr[NL*NL];
  for (int i = lane; i < NL*NL; i += 64) tr[i] = trans[i];
  __syncthreads();
  const bool act = lane < NL;
  const int j = act ? lane : 0;
  float alpha = act ? (start[j] + logits[(size_t)b*SEQ*NL + j]) : -3e38f;
  const int* tg = targets + (size_t)b*SEQ;
  for (int t = 1; t < SEQ; t++){
    if (tg[t] < 0) break;
    float e = logits[((size_t)b*SEQ + t)*NL + j];
    float v[NL]; float mx = -3e38f;
    #pragma unroll
    for (int i = 0; i < NL; i++){
      float ai = __shfl(alpha, i);
      v[i] = ai + tr[i*NL + j];
      mx = fmaxf(mx, v[i]);
    }
    float sum = 0.f;
    #pragma unroll
    for (int i = 0; i < NL; i++) sum += __expf(v[i] - mx);
    float nxt = mx + __logf(sum) + e;
    if (act) alpha = nxt;
  }
  float x = act ? alpha + endv[j] : -3e38f;
  float m2 = x;
  #pragma unroll
  for (int off = 32; off >= 1; off >>= 1) m2 = fmaxf(m2, __shfl_xor(m2, off));
  float se = __expf(x - m2);
  #pragma unroll
  for (int off = 32; off >= 1; off >>= 1) se += __shfl_xor(se, off);
  if (lane == 0) denom[b] = m2 + __logf(se);
}

__global__ void crf_final(const float* __restrict__ numlen, const float* __restrict__ denom,
                          float* __restrict__ out)
{
  if (blockIdx.x == 0 && threadIdx.x == 0){
    float sn = 0.f, sl = 0.f;
    for (int b = 0; b < 16; b++){ sn += numlen[b] - denom[b]; sl += numlen[16+b]; }
    out[0] = -sn / sl;
  }
}

// ---------------------------------------------------------------------------
extern "C" void kernel_launch(void* const* d_in, const int* in_sizes, int n_in,
                              void* d_out, int out_size, void* d_ws, size_t ws_size,
                              hipStream_t stream)
{
  const float* hidden  = (const float*)d_in[0];
  const int*   targets = (const int*)  d_in[1];
  const float* w_ih[4] = {(const float*)d_in[2], (const float*)d_in[6], (const float*)d_in[10], (const float*)d_in[14]};
  const float* w_hh[4] = {(const float*)d_in[3], (const float*)d_in[7], (const float*)d_in[11], (const float*)d_in[15]};
  const float* b_ih[4] = {(const float*)d_in[4], (const float*)d_in[8], (const float*)d_in[12], (const float*)d_in[16]};
  const float* b_hh[4] = {(const float*)d_in[5], (const float*)d_in[9], (const float*)d_in[13], (const float*)d_in[17]};
  const float* clf_w = (const float*)d_in[18];
  const float* clf_b = (const float*)d_in[19];
  const float* trans = (const float*)d_in[20];
  const float* start = (const float*)d_in[21];
  const float* endv  = (const float*)d_in[22];

  // workspace layout (~146 MB)
  char* p = (char*)d_ws;
  auto alloc = [&](size_t bytes){ void* r = (void*)p; p += (bytes + 255) & ~(size_t)255; return r; };
  u32*   WT2    = (u32*)  alloc((size_t)4*96*768*16*4);       // 18.9 MB packed W_hh
  float* bias   = (float*)alloc((size_t)4*G4*4);
  u16*   xg     = (u16*)  alloc((size_t)2*B*SEQ*G4*2);        // 100.7 MB
  u16*   h1     = (u16*)  alloc((size_t)B*SEQ*2*HD*2);        // 25.2 MB (doubles as th)
  float* hg     = (float*)alloc((size_t)2*2*768*16*4);        // 192 KB ping-pong h
  u32*   cnt    = (u32*)  alloc((size_t)2*(SEQ+1)*4);         // barrier counters
  float* logits = (float*)alloc((size_t)B*SEQ*NL*4);
  float* numlen = (float*)alloc(32*4);
  float* denom  = (float*)alloc(16*4);
  if ((size_t)(p - (char*)d_ws) > ws_size) return;

  WPtrs wp;
  for (int i = 0; i < 4; i++){ wp.w[i] = w_hh[i]; wp.bi[i] = b_ih[i]; wp.bh[i] = b_hh[i]; }
  prep_kernel<<<4096, 256, 0, stream>>>(wp, WT2, bias);

  const dim3 ggrid(24, 64);
  const size_t xg_dir = (size_t)B*SEQ*G4;
  const size_t wt2_layer = (size_t)2*96*768*16;
  const size_t hg_bytes  = (size_t)2*2*768*16*4;
  const size_t cnt_bytes = (size_t)2*(SEQ+1)*4;

  // ---- layer 0 ----
  gemm_xg<float><<<ggrid, 256, 0, stream>>>(hidden, HD, w_ih[0], bias + 0*G4, xg);
  gemm_xg<float><<<ggrid, 256, 0, stream>>>(hidden, HD, w_ih[1], bias + 1*G4, xg + xg_dir);
  hipMemsetAsync(hg, 0, hg_bytes, stream);
  hipMemsetAsync(cnt, 0, cnt_bytes, stream);
  {
    const u16* a0 = xg; const u32* a1 = WT2; float* a2 = hg; u32* a3 = cnt; u16* a4 = h1;
    void* args[] = { &a0, &a1, &a2, &a3, &a4 };
    hipLaunchCooperativeKernel(reinterpret_cast<void*>(&scan_kernel<0>),
                               dim3(192), dim3(256), args, 0, stream);
  }

  // ---- layer 1 ----
  gemm_xg<u16><<<ggrid, 256, 0, stream>>>(h1, 2*HD, w_ih[2], bias + 2*G4, xg);
  gemm_xg<u16><<<ggrid, 256, 0, stream>>>(h1, 2*HD, w_ih[3], bias + 3*G4, xg + xg_dir);
  hipMemsetAsync(hg, 0, hg_bytes, stream);
  hipMemsetAsync(cnt, 0, cnt_bytes, stream);
  {
    const u16* a0 = xg; const u32* a1 = WT2 + wt2_layer; float* a2 = hg; u32* a3 = cnt; u16* a4 = h1;
    void* args[] = { &a0, &a1, &a2, &a3, &a4 };
    hipLaunchCooperativeKernel(reinterpret_cast<void*>(&scan_kernel<1>),
                               dim3(192), dim3(256), args, 0, stream);
  }

  // ---- classifier + CRF ----
  logits_kernel<<<1024, 256, 0, stream>>>(h1, clf_w, clf_b, logits);
  crf_num<<<16, 256, 0, stream>>>(logits, targets, trans, start, endv, numlen);
  crf_fwd<<<16, 64, 0, stream>>>(logits, targets, trans, start, endv, denom);
  crf_final<<<1, 64, 0, stream>>>(numlen, denom, (float*)d_out);
}

// Round 4
// 8437.714 us; speedup vs baseline: 3.9488x; 1.3172x over previous
//
#include <hip/hip_runtime.h>
#include <cstdint>
#include <cstddef>

// Problem constants
#define B   16
#define SEQ 512
#define HD  768
#define G4  3072   // 4*HD
#define NL  25
#define NBLK 96    // blocks per direction in the scan

using u16 = unsigned short;
using u32 = uint32_t;
using u64 = unsigned long long;

__device__ __forceinline__ float bf2f(u16 u){
  union { float f; u32 i; } v; v.i = ((u32)u) << 16; return v.f;
}
__device__ __forceinline__ u16 f2bf(float f){
  union { float f; u32 i; } v; v.f = f;
  u32 r = v.i + 0x7FFFu + ((v.i >> 16) & 1u);  // RNE
  return (u16)(r >> 16);
}
__device__ __forceinline__ float asf(u32 u){ union { float f; u32 i; } v; v.i = u; return v.f; }
__device__ __forceinline__ float sigm(float x){ return 1.f/(1.f + __expf(-x)); }
__device__ __forceinline__ float tanhfast(float x){ return 1.f - 2.f/(__expf(2.f*x) + 1.f); }

struct __align__(8) us4 { u16 x, y, z, w; };

typedef __attribute__((ext_vector_type(8))) short bf16x8;
typedef __attribute__((ext_vector_type(4))) float f32x4;

// stage 8 bf16 (16B) into LDS from either bf16 or fp32 global source
__device__ __forceinline__ void stage_to_lds(u16* dst, const u16* src){
  *(uint4*)dst = *(const uint4*)src;
}
__device__ __forceinline__ void stage_to_lds(u16* dst, const float* src){
  float4 a = *(const float4*)src;
  float4 b = *(const float4*)(src + 4);
  uint4 v;
  v.x = (u32)f2bf(a.x) | ((u32)f2bf(a.y) << 16);
  v.y = (u32)f2bf(a.z) | ((u32)f2bf(a.w) << 16);
  v.z = (u32)f2bf(b.x) | ((u32)f2bf(b.y) << 16);
  v.w = (u32)f2bf(b.z) | ((u32)f2bf(b.w) << 16);
  *(uint4*)dst = v;
}

// ---------------------------------------------------------------------------
// prep: WT2[lid][jslot][k][jj] packed-bf16-pair layout for the scan kernel,
//       bias[lid][g] = b_ih + b_hh
// ---------------------------------------------------------------------------
struct WPtrs { const float* w[4]; const float* bi[4]; const float* bh[4]; };

__global__ void prep_kernel(WPtrs p, u32* __restrict__ WT2, float* __restrict__ bias){
  const int TOT = 4*96*768*16;
  for (int idx = blockIdx.x*blockDim.x + threadIdx.x; idx < TOT; idx += gridDim.x*blockDim.x){
    int jj  = idx & 15;
    int k   = (idx >> 4) % 768;
    int js  = ((idx >> 4) / 768) % 96;
    int lid = idx / (16*768*96);
    int jlo = 2*jj, jhi = 2*jj + 1;
    int jglo = (jlo >> 3)*768 + js*8 + (jlo & 7);
    int jghi = (jhi >> 3)*768 + js*8 + (jhi & 7);
    u16 lo = f2bf(p.w[lid][(size_t)jglo*HD + k]);
    u16 hi = f2bf(p.w[lid][(size_t)jghi*HD + k]);
    WT2[idx] = (u32)lo | ((u32)hi << 16);
  }
  for (int idx = blockIdx.x*blockDim.x + threadIdx.x; idx < 4*G4; idx += gridDim.x*blockDim.x){
    int lid = idx / G4, g = idx % G4;
    bias[idx] = p.bi[lid][g] + p.bh[lid][g];
  }
}

// ---------------------------------------------------------------------------
// MFMA xg GEMM: out[m][n] = bf16( sum_k A[m][k]*W[n][k] + bias[n] )
// M=8192, N=3072, K in {768,1536}. 128x128 block tile, 4 waves (2x2),
// 64x64 per wave = 4x4 frags of 16x16, mfma_f32_16x16x32_bf16, BK=32.
// fp32 sources converted to bf16 during staging (no extra buffers).
// LDS rows padded to 40 u16 (80B) -> bank stride 20, conflict-free-ish.
// ---------------------------------------------------------------------------
template<typename AT>
__global__ __launch_bounds__(256) void gemm_xg_mfma(const AT* __restrict__ A, int K,
    const float* __restrict__ W, const float* __restrict__ bias, u16* __restrict__ out)
{
  __shared__ u16 As[128][40];
  __shared__ u16 Bs[128][40];
  const int tid = threadIdx.x;
  const int bm = blockIdx.y * 128;
  const int bn = blockIdx.x * 128;
  const int wid = tid >> 6, lane = tid & 63;
  const int wr = wid >> 1, wc = wid & 1;     // wave tile origin (wr*64, wc*64)
  const int kq = lane >> 4, rl = lane & 15;  // frag k-chunk / row-col lane

  f32x4 acc[4][4];
  #pragma unroll
  for (int mf = 0; mf < 4; mf++)
    #pragma unroll
    for (int nf = 0; nf < 4; nf++) acc[mf][nf] = (f32x4){0.f,0.f,0.f,0.f};

  for (int k0 = 0; k0 < K; k0 += 32){
    #pragma unroll
    for (int u = 0; u < 2; u++){
      int c = tid + u*256;        // 512 chunks of 16B per tile
      int r = c >> 2, q = c & 3;
      stage_to_lds(&As[r][q*8], A + (size_t)(bm + r)*K + k0 + q*8);
      stage_to_lds(&Bs[r][q*8], W + (size_t)(bn + r)*K + k0 + q*8);
    }
    __syncthreads();
    bf16x8 af[4], bfr[4];
    #pragma unroll
    for (int mf = 0; mf < 4; mf++) af[mf]  = *(const bf16x8*)&As[wr*64 + mf*16 + rl][kq*8];
    #pragma unroll
    for (int nf = 0; nf < 4; nf++) bfr[nf] = *(const bf16x8*)&Bs[wc*64 + nf*16 + rl][kq*8];
    #pragma unroll
    for (int mf = 0; mf < 4; mf++)
      #pragma unroll
      for (int nf = 0; nf < 4; nf++)
        acc[mf][nf] = __builtin_amdgcn_mfma_f32_16x16x32_bf16(af[mf], bfr[nf], acc[mf][nf], 0, 0, 0);
    __syncthreads();
  }

  // epilogue: C/D layout col=lane&15, row=(lane>>4)*4+i  [verified mapping]
  float bv[4];
  #pragma unroll
  for (int nf = 0; nf < 4; nf++) bv[nf] = bias[bn + wc*64 + nf*16 + rl];
  #pragma unroll
  for (int mf = 0; mf < 4; mf++){
    #pragma unroll
    for (int i = 0; i < 4; i++){
      size_t row = (size_t)bm + wr*64 + mf*16 + kq*4 + i;
      u16* op = out + row*G4 + bn + wc*64 + rl;
      #pragma unroll
      for (int nf = 0; nf < 4; nf++)
        op[nf*16] = f2bf(acc[mf][nf][i] + bv[nf]);
    }
  }
}

// ---------------------------------------------------------------------------
// Persistent LSTM scan, per-block flag barrier + packed-bf16 h exchange.
// 192 blocks x 256 thr. Block: dir = bid/96, js = bid%96 (8 h-units).
// Producers: relaxed atomic STORE flag[js]=s+1 (no RMW serialization).
// Consumers: 96 threads each spin on their own flag.
// h exchange: hgb[ping][dir][k][b-pair] u32 (2 bf16), 24KB/dir/step.
// ---------------------------------------------------------------------------
template<int LAYER>
__global__ __launch_bounds__(256, 1) void scan_kernel(
    const u16* __restrict__ xg,      // [dir][b*SEQ+t][G4]
    const u32* __restrict__ WT2,     // [dir][96][768][16] (this layer's slice)
    u32* __restrict__ hgb,           // [2 ping][2 dir][768][8] packed bf16 pairs
    u32* __restrict__ flags,         // [2 dir][96], zeroed
    u16* __restrict__ hout)          // [b*SEQ+t][1536]
{
  __shared__ u32  Wl[768*16];     // 48 KB packed bf16 pairs, [k][jj]
  __shared__ float hL[768*16];    // 48 KB, [k][b] fp32
  __shared__ float red2[512*4];   // 8 KB
  __shared__ float cL[128];       // c state

  const int tid = threadIdx.x;
  const int dir = blockIdx.x / NBLK;
  const int js  = blockIdx.x % NBLK;

  { // stage W once
    const uint4* src = (const uint4*)(WT2 + (size_t)(dir*NBLK + js)*768*16);
    uint4* dst = (uint4*)Wl;
    #pragma unroll
    for (int i = 0; i < 12; i++) dst[i*256 + tid] = src[i*256 + tid];
  }
  if (tid < 128) cL[tid] = 0.f;
  __syncthreads();

  const int jg = tid & 3;            // gate index
  const int bg = (tid >> 2) & 3;     // batch quad
  const int ks = tid >> 4;           // k-slice 0..15
  const int jh_l = tid >> 4;         // gate-phase j (tid<128)
  const int b_g  = tid & 15;

  u32* myflags = flags + dir*NBLK;

  for (int s = 0; s < SEQ; s++){
    const int t_seq = dir ? (SEQ-1-s) : s;

    // xg prefetch BEFORE the barrier poll: latency hides under the wait
    float xgv[4];
    if (tid < 128){
      const u16* xp = xg + (((size_t)(dir*B + b_g))*SEQ + t_seq)*G4 + js*8 + jh_l;
      #pragma unroll
      for (int g = 0; g < 4; g++) xgv[g] = bf2f(xp[g*HD]);
    }

    // wait for all 96 producer blocks of this dir to publish H[s]
    if (s > 0){
      if (tid < NBLK){
        while (__hip_atomic_load(&myflags[tid], __ATOMIC_RELAXED, __HIP_MEMORY_SCOPE_AGENT) < (u32)s)
          __builtin_amdgcn_s_sleep(1);
      }
      __syncthreads();
    }

    // load H[s] (packed bf16) from coherent point -> fp32 LDS
    {
      const u64* src = (const u64*)(hgb + (size_t)((s&1)*2 + dir)*(768*8));
      u64 tmp[12];
      #pragma unroll
      for (int i = 0; i < 12; i++)
        tmp[i] = __hip_atomic_load(&src[i*256 + tid], __ATOMIC_RELAXED, __HIP_MEMORY_SCOPE_AGENT);
      #pragma unroll
      for (int i = 0; i < 12; i++){
        u32 lo = (u32)tmp[i], hi = (u32)(tmp[i] >> 32);
        ((float4*)hL)[i*256 + tid] =
          make_float4(asf(lo << 16), asf(lo & 0xffff0000u),
                      asf(hi << 16), asf(hi & 0xffff0000u));
      }
    }
    __syncthreads();

    // compute: acc[j 8][b 4] over 48 k values (k = ks + 16*i)
    float acc[8][4];
    #pragma unroll
    for (int a = 0; a < 8; a++)
      #pragma unroll
      for (int b2 = 0; b2 < 4; b2++) acc[a][b2] = 0.f;

    #pragma unroll 4
    for (int i = 0; i < 48; i++){
      const int k = ks + (i << 4);
      uint4 wv  = *(const uint4*)&Wl[k*16 + jg*4];
      float4 hv = *(const float4*)&hL[k*16 + bg*4];
      float wj[8];
      wj[0]=asf(wv.x<<16); wj[1]=asf(wv.x&0xffff0000u);
      wj[2]=asf(wv.y<<16); wj[3]=asf(wv.y&0xffff0000u);
      wj[4]=asf(wv.z<<16); wj[5]=asf(wv.z&0xffff0000u);
      wj[6]=asf(wv.w<<16); wj[7]=asf(wv.w&0xffff0000u);
      const float hb[4] = {hv.x, hv.y, hv.z, hv.w};
      #pragma unroll
      for (int a = 0; a < 8; a++)
        #pragma unroll
        for (int b2 = 0; b2 < 4; b2++)
          acc[a][b2] = fmaf(wj[a], hb[b2], acc[a][b2]);
    }

    // ks-reduce: 4-way within wave via shfl, 4 waves via LDS
    const int wv_id = tid >> 6;
    #pragma unroll
    for (int a = 0; a < 8; a++)
      #pragma unroll
      for (int b2 = 0; b2 < 4; b2++){
        float v = acc[a][b2];
        v += __shfl_xor(v, 16);
        v += __shfl_xor(v, 32);
        if ((tid & 48) == 0){
          int out = (jg*8 + a)*16 + bg*4 + b2;
          red2[out*4 + wv_id] = v;
        }
      }
    __syncthreads();

    // gates + state update + h publish (packed bf16)
    if (tid < 128){
      float gs[4];
      #pragma unroll
      for (int g = 0; g < 4; g++){
        int out = (g*8 + jh_l)*16 + b_g;
        float4 r = *(const float4*)&red2[out*4];
        gs[g] = r.x + r.y + r.z + r.w + xgv[g];
      }
      float c  = cL[tid];
      float ct = sigm(gs[1])*c + sigm(gs[0])*tanhfast(gs[2]);
      float h  = sigm(gs[3])*tanhfast(ct);
      cL[tid] = ct;

      u32 hb16 = (u32)f2bf(h);
      u32 other = (u32)__shfl_xor((int)hb16, 1);
      if ((tid & 1) == 0){
        u32 pair = (hb16 & 0xffffu) | (other << 16);
        u32* hdst = hgb + (size_t)(((s+1)&1)*2 + dir)*(768*8);
        __hip_atomic_store(&hdst[(js*8 + jh_l)*8 + (b_g >> 1)], pair,
                           __ATOMIC_RELAXED, __HIP_MEMORY_SCOPE_AGENT);
      }
      int jhg = js*8 + jh_l;
      float hw = (LAYER == 0) ? h : tanhfast(h);
      hout[((size_t)b_g*SEQ + t_seq)*1536 + dir*HD + jhg] = f2bf(hw);
    }
    __syncthreads();   // drains vmcnt before s_barrier -> h stores complete
    if (tid == 0)
      __hip_atomic_store(&myflags[js], (u32)(s+1), __ATOMIC_RELAXED, __HIP_MEMORY_SCOPE_AGENT);
  }
}

// ---------------------------------------------------------------------------
// logits[row][l] = tanh(h2)[row] . clf_w[l] + clf_b[l]  (th already tanh'd)
// ---------------------------------------------------------------------------
__global__ __launch_bounds__(256) void logits_kernel(const u16* __restrict__ th,
    const float* __restrict__ clf_w, const float* __restrict__ clf_b,
    float* __restrict__ logits)
{
  __shared__ u16 xl[8*1536];
  const int tid = threadIdx.x;
  const int row0 = blockIdx.x * 8;
  {
    const uint4* src = (const uint4*)(th + (size_t)row0*1536);
    uint4* dst = (uint4*)xl;
    #pragma unroll
    for (int i = 0; i < 6; i++) dst[i*256 + tid] = src[i*256 + tid];
  }
  __syncthreads();
  const int r = tid >> 5, l = tid & 31;
  if (l < NL){
    float acc = clf_b[l];
    const float* wr = clf_w + (size_t)l*1536;
    #pragma unroll 2
    for (int kk = 0; kk < 192; kk++){
      uint4 xv = *(const uint4*)&xl[r*1536 + kk*8];
      float4 w0 = *(const float4*)(wr + kk*8);
      float4 w1 = *(const float4*)(wr + kk*8 + 4);
      acc = fmaf(asf(xv.x<<16), w0.x, acc); acc = fmaf(asf(xv.x&0xffff0000u), w0.y, acc);
      acc = fmaf(asf(xv.y<<16), w0.z, acc); acc = fmaf(asf(xv.y&0xffff0000u), w0.w, acc);
      acc = fmaf(asf(xv.z<<16), w1.x, acc); acc = fmaf(asf(xv.z&0xffff0000u), w1.y, acc);
      acc = fmaf(asf(xv.w<<16), w1.z, acc); acc = fmaf(asf(xv.w&0xffff0000u), w1.w, acc);
    }
    logits[(size_t)(row0 + r)*NL + l] = acc;
  }
}

// ---------------------------------------------------------------------------
// CRF numerator + lengths (per b)
// ---------------------------------------------------------------------------
__global__ __launch_bounds__(256) void crf_num(const float* __restrict__ logits,
    const int* __restrict__ targets, const float* __restrict__ trans,
    const float* __restrict__ start, const float* __restrict__ endv,
    float* __restrict__ numlen)
{
  const int b = blockIdx.x;
  const int* tg = targets + (size_t)b*SEQ;
  float s = 0.f; int cnt = 0;
  for (int t = threadIdx.x; t < SEQ; t += 256){
    int cur = tg[t];
    if (cur >= 0){
      cnt++;
      float e = logits[((size_t)b*SEQ + t)*NL + cur];
      s += e;
      if (t > 0) s += trans[tg[t-1]*NL + cur];
    }
  }
  __shared__ float ss[256]; __shared__ int sc[256];
  ss[threadIdx.x] = s; sc[threadIdx.x] = cnt;
  __syncthreads();
  for (int o = 128; o > 0; o >>= 1){
    if (threadIdx.x < o){ ss[threadIdx.x] += ss[threadIdx.x+o]; sc[threadIdx.x] += sc[threadIdx.x+o]; }
    __syncthreads();
  }
  if (threadIdx.x == 0){
    int len = sc[0];
    numlen[b]      = ss[0] + start[tg[0]] + endv[tg[len-1]];
    numlen[16 + b] = (float)len;
  }
}

// ---------------------------------------------------------------------------
// CRF forward algorithm (denominator), one wave per b
// ---------------------------------------------------------------------------
__global__ __launch_bounds__(64) void crf_fwd(const float* __restrict__ logits,
    const int* __restrict__ targets, const float* __restrict__ trans,
    const float* __restrict__ start, const float* __restrict__ endv,
    float* __restrict__ denom)
{
  const int b = blockIdx.x, lane = threadIdx.x;
  __shared__ float tr[NL*NL];
  for (int i = lane; i < NL*NL; i += 64) tr[i] = trans[i];
  __syncthreads();
  const bool act = lane < NL;
  const int j = act ? lane : 0;
  float alpha = act ? (start[j] + logits[(size_t)b*SEQ*NL + j]) : -3e38f;
  const int* tg = targets + (size_t)b*SEQ;
  for (int t = 1; t < SEQ; t++){
    if (tg[t] < 0) break;
    float e = logits[((size_t)b*SEQ + t)*NL + j];
    float v[NL]; float mx = -3e38f;
    #pragma unroll
    for (int i = 0; i < NL; i++){
      float ai = __shfl(alpha, i);
      v[i] = ai + tr[i*NL + j];
      mx = fmaxf(mx, v[i]);
    }
    float sum = 0.f;
    #pragma unroll
    for (int i = 0; i < NL; i++) sum += __expf(v[i] - mx);
    float nxt = mx + __logf(sum) + e;
    if (act) alpha = nxt;
  }
  float x = act ? alpha + endv[j] : -3e38f;
  float m2 = x;
  #pragma unroll
  for (int off = 32; off >= 1; off >>= 1) m2 = fmaxf(m2, __shfl_xor(m2, off));
  float se = __expf(x - m2);
  #pragma unroll
  for (int off = 32; off >= 1; off >>= 1) se += __shfl_xor(se, off);
  if (lane == 0) denom[b] = m2 + __logf(se);
}

__global__ void crf_final(const float* __restrict__ numlen, const float* __restrict__ denom,
                          float* __restrict__ out)
{
  if (blockIdx.x == 0 && threadIdx.x == 0){
    float sn = 0.f, sl = 0.f;
    for (int b = 0; b < 16; b++){ sn += numlen[b] - denom[b]; sl += numlen[16+b]; }
    out[0] = -sn / sl;
  }
}

// ---------------------------------------------------------------------------
extern "C" void kernel_launch(void* const* d_in, const int* in_sizes, int n_in,
                              void* d_out, int out_size, void* d_ws, size_t ws_size,
                              hipStream_t stream)
{
  const float* hidden  = (const float*)d_in[0];
  const int*   targets = (const int*)  d_in[1];
  const float* w_ih[4] = {(const float*)d_in[2], (const float*)d_in[6], (const float*)d_in[10], (const float*)d_in[14]};
  const float* w_hh[4] = {(const float*)d_in[3], (const float*)d_in[7], (const float*)d_in[11], (const float*)d_in[15]};
  const float* b_ih[4] = {(const float*)d_in[4], (const float*)d_in[8], (const float*)d_in[12], (const float*)d_in[16]};
  const float* b_hh[4] = {(const float*)d_in[5], (const float*)d_in[9], (const float*)d_in[13], (const float*)d_in[17]};
  const float* clf_w = (const float*)d_in[18];
  const float* clf_b = (const float*)d_in[19];
  const float* trans = (const float*)d_in[20];
  const float* start = (const float*)d_in[21];
  const float* endv  = (const float*)d_in[22];

  // workspace layout (~146 MB)
  char* p = (char*)d_ws;
  auto alloc = [&](size_t bytes){ void* r = (void*)p; p += (bytes + 255) & ~(size_t)255; return r; };
  u32*   WT2    = (u32*)  alloc((size_t)4*96*768*16*4);       // 18.9 MB packed W_hh
  float* bias   = (float*)alloc((size_t)4*G4*4);
  u16*   xg     = (u16*)  alloc((size_t)2*B*SEQ*G4*2);        // 100.7 MB
  u16*   h1     = (u16*)  alloc((size_t)B*SEQ*2*HD*2);        // 25.2 MB (doubles as th)
  u32*   hgb    = (u32*)  alloc((size_t)2*2*768*8*4);         // 98 KB packed h ping-pong
  u32*   flags  = (u32*)  alloc((size_t)2*NBLK*4);            // barrier flags
  float* logits = (float*)alloc((size_t)B*SEQ*NL*4);
  float* numlen = (float*)alloc(32*4);
  float* denom  = (float*)alloc(16*4);
  if ((size_t)(p - (char*)d_ws) > ws_size) return;

  WPtrs wp;
  for (int i = 0; i < 4; i++){ wp.w[i] = w_hh[i]; wp.bi[i] = b_ih[i]; wp.bh[i] = b_hh[i]; }
  prep_kernel<<<4096, 256, 0, stream>>>(wp, WT2, bias);

  const dim3 ggrid(24, 64);
  const size_t xg_dir = (size_t)B*SEQ*G4;
  const size_t wt2_layer = (size_t)2*96*768*16;
  const size_t hgb_bytes  = (size_t)2*2*768*8*4;
  const size_t flg_bytes  = (size_t)2*NBLK*4;

  // ---- layer 0 ----
  gemm_xg_mfma<float><<<ggrid, 256, 0, stream>>>(hidden, HD, w_ih[0], bias + 0*G4, xg);
  gemm_xg_mfma<float><<<ggrid, 256, 0, stream>>>(hidden, HD, w_ih[1], bias + 1*G4, xg + xg_dir);
  hipMemsetAsync(hgb, 0, hgb_bytes, stream);
  hipMemsetAsync(flags, 0, flg_bytes, stream);
  {
    const u16* a0 = xg; const u32* a1 = WT2; u32* a2 = hgb; u32* a3 = flags; u16* a4 = h1;
    void* args[] = { &a0, &a1, &a2, &a3, &a4 };
    hipLaunchCooperativeKernel(reinterpret_cast<void*>(&scan_kernel<0>),
                               dim3(192), dim3(256), args, 0, stream);
  }

  // ---- layer 1 ----
  gemm_xg_mfma<u16><<<ggrid, 256, 0, stream>>>(h1, 2*HD, w_ih[2], bias + 2*G4, xg);
  gemm_xg_mfma<u16><<<ggrid, 256, 0, stream>>>(h1, 2*HD, w_ih[3], bias + 3*G4, xg + xg_dir);
  hipMemsetAsync(hgb, 0, hgb_bytes, stream);
  hipMemsetAsync(flags, 0, flg_bytes, stream);
  {
    const u16* a0 = xg; const u32* a1 = WT2 + wt2_layer; u32* a2 = hgb; u32* a3 = flags; u16* a4 = h1;
    void* args[] = { &a0, &a1, &a2, &a3, &a4 };
    hipLaunchCooperativeKernel(reinterpret_cast<void*>(&scan_kernel<1>),
                               dim3(192), dim3(256), args, 0, stream);
  }

  // ---- classifier + CRF ----
  logits_kernel<<<1024, 256, 0, stream>>>(h1, clf_w, clf_b, logits);
  crf_num<<<16, 256, 0, stream>>>(logits, targets, trans, start, endv, numlen);
  crf_fwd<<<16, 64, 0, stream>>>(logits, targets, trans, start, endv, denom);
  crf_final<<<1, 64, 0, stream>>>(numlen, denom, (float*)d_out);
}

// Round 5
// 4082.726 us; speedup vs baseline: 8.1609x; 2.0667x over previous
//
#include <hip/hip_runtime.h>
#include <cstdint>
#include <cstddef>

// Problem constants
#define B   16
#define SEQ 512
#define HD  768
#define G4  3072   // 4*HD
#define NL  25
#define NBLK 96    // blocks per direction in the scan

using u16 = unsigned short;
using u32 = uint32_t;
using u64 = unsigned long long;

__device__ __forceinline__ float bf2f(u16 u){
  union { float f; u32 i; } v; v.i = ((u32)u) << 16; return v.f;
}
__device__ __forceinline__ u16 f2bf(float f){
  union { float f; u32 i; } v; v.f = f;
  u32 r = v.i + 0x7FFFu + ((v.i >> 16) & 1u);  // RNE
  return (u16)(r >> 16);
}
__device__ __forceinline__ float asf(u32 u){ union { float f; u32 i; } v; v.i = u; return v.f; }
__device__ __forceinline__ float sigm(float x){ return 1.f/(1.f + __expf(-x)); }
__device__ __forceinline__ float tanhfast(float x){ return 1.f - 2.f/(__expf(2.f*x) + 1.f); }

typedef __attribute__((ext_vector_type(8))) short bf16x8;
typedef __attribute__((ext_vector_type(4))) float f32x4;

// stage 8 bf16 (16B) into LDS from either bf16 or fp32 global source
__device__ __forceinline__ void stage_to_lds(u16* dst, const u16* src){
  *(uint4*)dst = *(const uint4*)src;
}
__device__ __forceinline__ void stage_to_lds(u16* dst, const float* src){
  float4 a = *(const float4*)src;
  float4 b = *(const float4*)(src + 4);
  uint4 v;
  v.x = (u32)f2bf(a.x) | ((u32)f2bf(a.y) << 16);
  v.y = (u32)f2bf(a.z) | ((u32)f2bf(a.w) << 16);
  v.z = (u32)f2bf(b.x) | ((u32)f2bf(b.y) << 16);
  v.w = (u32)f2bf(b.z) | ((u32)f2bf(b.w) << 16);
  *(uint4*)dst = v;
}

// ---------------------------------------------------------------------------
// prep: bias[lid][g] = b_ih + b_hh   (W_hh now consumed directly by the scan)
// ---------------------------------------------------------------------------
struct BPtrs { const float* bi[4]; const float* bh[4]; };

__global__ void prep_bias(BPtrs p, float* __restrict__ bias){
  int idx = blockIdx.x*blockDim.x + threadIdx.x;
  if (idx < 4*G4){
    int lid = idx / G4, g = idx % G4;
    bias[idx] = p.bi[lid][g] + p.bh[lid][g];
  }
}

// ---------------------------------------------------------------------------
// MFMA xg GEMM: out[m][n] = bf16( sum_k A[m][k]*W[n][k] + bias[n] )
// (unchanged from round 4 — verified)
// ---------------------------------------------------------------------------
template<typename AT>
__global__ __launch_bounds__(256) void gemm_xg_mfma(const AT* __restrict__ A, int K,
    const float* __restrict__ W, const float* __restrict__ bias, u16* __restrict__ out)
{
  __shared__ u16 As[128][40];
  __shared__ u16 Bs[128][40];
  const int tid = threadIdx.x;
  const int bm = blockIdx.y * 128;
  const int bn = blockIdx.x * 128;
  const int wid = tid >> 6, lane = tid & 63;
  const int wr = wid >> 1, wc = wid & 1;
  const int kq = lane >> 4, rl = lane & 15;

  f32x4 acc[4][4];
  #pragma unroll
  for (int mf = 0; mf < 4; mf++)
    #pragma unroll
    for (int nf = 0; nf < 4; nf++) acc[mf][nf] = (f32x4){0.f,0.f,0.f,0.f};

  for (int k0 = 0; k0 < K; k0 += 32){
    #pragma unroll
    for (int u = 0; u < 2; u++){
      int c = tid + u*256;
      int r = c >> 2, q = c & 3;
      stage_to_lds(&As[r][q*8], A + (size_t)(bm + r)*K + k0 + q*8);
      stage_to_lds(&Bs[r][q*8], W + (size_t)(bn + r)*K + k0 + q*8);
    }
    __syncthreads();
    bf16x8 af[4], bfr[4];
    #pragma unroll
    for (int mf = 0; mf < 4; mf++) af[mf]  = *(const bf16x8*)&As[wr*64 + mf*16 + rl][kq*8];
    #pragma unroll
    for (int nf = 0; nf < 4; nf++) bfr[nf] = *(const bf16x8*)&Bs[wc*64 + nf*16 + rl][kq*8];
    #pragma unroll
    for (int mf = 0; mf < 4; mf++)
      #pragma unroll
      for (int nf = 0; nf < 4; nf++)
        acc[mf][nf] = __builtin_amdgcn_mfma_f32_16x16x32_bf16(af[mf], bfr[nf], acc[mf][nf], 0, 0, 0);
    __syncthreads();
  }

  float bv[4];
  #pragma unroll
  for (int nf = 0; nf < 4; nf++) bv[nf] = bias[bn + wc*64 + nf*16 + rl];
  #pragma unroll
  for (int mf = 0; mf < 4; mf++){
    #pragma unroll
    for (int i = 0; i < 4; i++){
      size_t row = (size_t)bm + wr*64 + mf*16 + kq*4 + i;
      u16* op = out + row*G4 + bn + wc*64 + rl;
      #pragma unroll
      for (int nf = 0; nf < 4; nf++)
        op[nf*16] = f2bf(acc[mf][nf][i] + bv[nf]);
    }
  }
}

// ---------------------------------------------------------------------------
// Persistent LSTM scan, MFMA compute + register-resident W_hh + direct-to-reg
// h exchange. 192 blocks x 256 thr (4 waves). Block: dir = bid/96, js = bid%96
// (8 h-units = 32 gate rows). Waves split K=768 into 4x192.
// Per step: prefetch xg -> poll flags -> B-frags (h) via u64 atomic loads
// from hgb[b][k] -> 12 MFMA -> LDS cross-wave reduce -> gates -> publish h
// (bf16 pairs) -> drain -> flag -> hout (off critical path).
// ---------------------------------------------------------------------------
template<int LAYER>
__global__ __launch_bounds__(256, 1) void scan_kernel(
    const u16* __restrict__ xg,      // [dir][b*SEQ+t][G4]
    const float* __restrict__ whh_f, // [3072][768] forward dir
    const float* __restrict__ whh_r, // reverse dir
    u16* __restrict__ hgbu,          // [2 ping][2 dir][16 b][768 k] bf16
    u32* __restrict__ flags,         // [2 dir][NBLK], zeroed
    u16* __restrict__ hout)          // [b*SEQ+t][1536]
{
  __shared__ float red[32*16*4];   // [j_local][b][wave], 8 KB
  __shared__ float cL[128];        // c state [jh_l][b]

  const int tid  = threadIdx.x;
  const int dir  = blockIdx.x / NBLK;
  const int js   = blockIdx.x % NBLK;
  const int w    = tid >> 6;
  const int lane = tid & 63;
  const int lr   = lane & 15;   // M-row (j) for A / N-col (b) for B
  const int lq   = lane >> 4;   // k-octet selector

  const float* Wsrc = dir ? whh_r : whh_f;

  // one-time A-frag preload: af[m][c] covers j = m*16+lr, k = w*192+c*32+lq*8
  bf16x8 af[2][6];
  #pragma unroll
  for (int m = 0; m < 2; m++){
    int j_local = m*16 + lr;
    int j_glob  = (j_local >> 3)*768 + js*8 + (j_local & 7);  // gate-major rows
    const float* rowp = Wsrc + (size_t)j_glob*HD;
    #pragma unroll
    for (int c = 0; c < 6; c++){
      int k = w*192 + c*32 + lq*8;
      float4 a  = *(const float4*)(rowp + k);
      float4 b4 = *(const float4*)(rowp + k + 4);
      union { u32 u[4]; bf16x8 v; } t;
      t.u[0] = (u32)f2bf(a.x)  | ((u32)f2bf(a.y)  << 16);
      t.u[1] = (u32)f2bf(a.z)  | ((u32)f2bf(a.w)  << 16);
      t.u[2] = (u32)f2bf(b4.x) | ((u32)f2bf(b4.y) << 16);
      t.u[3] = (u32)f2bf(b4.z) | ((u32)f2bf(b4.w) << 16);
      af[m][c] = t.v;
    }
  }
  if (tid < 128) cL[tid] = 0.f;
  __syncthreads();

  const int jh_l = tid >> 4;    // 0..7 (valid for tid<128)
  const int b_g  = tid & 15;
  u32* myflags = flags + dir*NBLK;

  for (int s = 0; s < SEQ; s++){
    const int t_seq = dir ? (SEQ-1-s) : s;

    // xg prefetch before the poll: HBM latency hides under the wait
    float xgv[4];
    if (tid < 128){
      const u16* xp = xg + (((size_t)(dir*B + b_g))*SEQ + t_seq)*G4 + js*8 + jh_l;
      #pragma unroll
      for (int g = 0; g < 4; g++) xgv[g] = bf2f(xp[g*HD]);
    }

    if (s > 0){
      if (tid < NBLK){
        while (__hip_atomic_load(&myflags[tid], __ATOMIC_RELAXED, __HIP_MEMORY_SCOPE_AGENT) < (u32)s)
          __builtin_amdgcn_s_sleep(1);
      }
      __syncthreads();
    }

    // B-frags (h) direct to registers from the coherent point
    const u16* hb = hgbu + (size_t)((s&1)*2 + dir)*(16*768) + lr*768;
    u64 bq[6][2];
    #pragma unroll
    for (int c = 0; c < 6; c++){
      const u64* p = (const u64*)(hb + w*192 + c*32 + lq*8);
      bq[c][0] = __hip_atomic_load(p,     __ATOMIC_RELAXED, __HIP_MEMORY_SCOPE_AGENT);
      bq[c][1] = __hip_atomic_load(p + 1, __ATOMIC_RELAXED, __HIP_MEMORY_SCOPE_AGENT);
    }

    f32x4 acc0 = (f32x4){0.f,0.f,0.f,0.f};
    f32x4 acc1 = (f32x4){0.f,0.f,0.f,0.f};
    #pragma unroll
    for (int c = 0; c < 6; c++){
      union { u64 q[2]; bf16x8 v; } bu;
      bu.q[0] = bq[c][0]; bu.q[1] = bq[c][1];
      acc0 = __builtin_amdgcn_mfma_f32_16x16x32_bf16(af[0][c], bu.v, acc0, 0, 0, 0);
      acc1 = __builtin_amdgcn_mfma_f32_16x16x32_bf16(af[1][c], bu.v, acc1, 0, 0, 0);
    }

    // cross-wave K reduce via LDS: D[j= (lq*4+i) (+16 for acc1)][b=lr]
    #pragma unroll
    for (int i = 0; i < 4; i++){
      red[(( 0 + lq*4 + i)*16 + lr)*4 + w] = acc0[i];
      red[((16 + lq*4 + i)*16 + lr)*4 + w] = acc1[i];
    }
    __syncthreads();

    const bool more = (s + 1 < SEQ);
    u32 opair = 0;
    if (tid < 128){
      float gs[4];
      #pragma unroll
      for (int g = 0; g < 4; g++){
        const float4 r4 = *(const float4*)&red[((g*8 + jh_l)*16 + b_g)*4];
        gs[g] = r4.x + r4.y + r4.z + r4.w + xgv[g];
      }
      float c  = cL[tid];
      float ct = sigm(gs[1])*c + sigm(gs[0])*tanhfast(gs[2]);
      float h  = sigm(gs[3])*tanhfast(ct);
      cL[tid] = ct;

      // pack pairs along k via shfl (jh_l even/odd at same b)
      u32 hb16 = (u32)f2bf(h);
      u32 hoth = (u32)__shfl_xor((int)hb16, 16);
      float hw = (LAYER == 0) ? h : tanhfast(h);
      u32 ob16 = (u32)f2bf(hw);
      u32 ooth = (u32)__shfl_xor((int)ob16, 16);
      opair = (ob16 & 0xffffu) | (ooth << 16);

      if (more && (tid & 16) == 0){
        u32 pair = (hb16 & 0xffffu) | (hoth << 16);
        u16* hdst = hgbu + (size_t)(((s+1)&1)*2 + dir)*(16*768) + b_g*768 + js*8 + jh_l;
        __hip_atomic_store((u32*)hdst, pair, __ATOMIC_RELAXED, __HIP_MEMORY_SCOPE_AGENT);
      }
    }
    if (more){
      __syncthreads();   // drains vmcnt -> h publish visible before flag
      if (tid == 0)
        __hip_atomic_store(&myflags[js], (u32)(s+1), __ATOMIC_RELAXED, __HIP_MEMORY_SCOPE_AGENT);
    }
    // hout write AFTER the flag: off the inter-block critical path
    if (tid < 128 && (tid & 16) == 0){
      u16* od = hout + ((size_t)b_g*SEQ + t_seq)*1536 + dir*HD + js*8 + jh_l;
      *(u32*)od = opair;
    }
  }
}

// ---------------------------------------------------------------------------
// logits[row][l] = tanh(h2)[row] . clf_w[l] + clf_b[l]  (th already tanh'd)
// ---------------------------------------------------------------------------
__global__ __launch_bounds__(256) void logits_kernel(const u16* __restrict__ th,
    const float* __restrict__ clf_w, const float* __restrict__ clf_b,
    float* __restrict__ logits)
{
  __shared__ u16 xl[8*1536];
  const int tid = threadIdx.x;
  const int row0 = blockIdx.x * 8;
  {
    const uint4* src = (const uint4*)(th + (size_t)row0*1536);
    uint4* dst = (uint4*)xl;
    #pragma unroll
    for (int i = 0; i < 6; i++) dst[i*256 + tid] = src[i*256 + tid];
  }
  __syncthreads();
  const int r = tid >> 5, l = tid & 31;
  if (l < NL){
    float acc = clf_b[l];
    const float* wr = clf_w + (size_t)l*1536;
    #pragma unroll 2
    for (int kk = 0; kk < 192; kk++){
      uint4 xv = *(const uint4*)&xl[r*1536 + kk*8];
      float4 w0 = *(const float4*)(wr + kk*8);
      float4 w1 = *(const float4*)(wr + kk*8 + 4);
      acc = fmaf(asf(xv.x<<16), w0.x, acc); acc = fmaf(asf(xv.x&0xffff0000u), w0.y, acc);
      acc = fmaf(asf(xv.y<<16), w0.z, acc); acc = fmaf(asf(xv.y&0xffff0000u), w0.w, acc);
      acc = fmaf(asf(xv.z<<16), w1.x, acc); acc = fmaf(asf(xv.z&0xffff0000u), w1.y, acc);
      acc = fmaf(asf(xv.w<<16), w1.z, acc); acc = fmaf(asf(xv.w&0xffff0000u), w1.w, acc);
    }
    logits[(size_t)(row0 + r)*NL + l] = acc;
  }
}

// ---------------------------------------------------------------------------
// CRF numerator + lengths (per b)
// ---------------------------------------------------------------------------
__global__ __launch_bounds__(256) void crf_num(const float* __restrict__ logits,
    const int* __restrict__ targets, const float* __restrict__ trans,
    const float* __restrict__ start, const float* __restrict__ endv,
    float* __restrict__ numlen)
{
  const int b = blockIdx.x;
  const int* tg = targets + (size_t)b*SEQ;
  float s = 0.f; int cnt = 0;
  for (int t = threadIdx.x; t < SEQ; t += 256){
    int cur = tg[t];
    if (cur >= 0){
      cnt++;
      float e = logits[((size_t)b*SEQ + t)*NL + cur];
      s += e;
      if (t > 0) s += trans[tg[t-1]*NL + cur];
    }
  }
  __shared__ float ss[256]; __shared__ int sc[256];
  ss[threadIdx.x] = s; sc[threadIdx.x] = cnt;
  __syncthreads();
  for (int o = 128; o > 0; o >>= 1){
    if (threadIdx.x < o){ ss[threadIdx.x] += ss[threadIdx.x+o]; sc[threadIdx.x] += sc[threadIdx.x+o]; }
    __syncthreads();
  }
  if (threadIdx.x == 0){
    int len = sc[0];
    numlen[b]      = ss[0] + start[tg[0]] + endv[tg[len-1]];
    numlen[16 + b] = (float)len;
  }
}

// ---------------------------------------------------------------------------
// CRF forward algorithm (denominator), one wave per b
// ---------------------------------------------------------------------------
__global__ __launch_bounds__(64) void crf_fwd(const float* __restrict__ logits,
    const int* __restrict__ targets, const float* __restrict__ trans,
    const float* __restrict__ start, const float* __restrict__ endv,
    float* __restrict__ denom)
{
  const int b = blockIdx.x, lane = threadIdx.x;
  __shared__ float tr[NL*NL];
  for (int i = lane; i < NL*NL; i += 64) tr[i] = trans[i];
  __syncthreads();
  const bool act = lane < NL;
  const int j = act ? lane : 0;
  float alpha = act ? (start[j] + logits[(size_t)b*SEQ*NL + j]) : -3e38f;
  const int* tg = targets + (size_t)b*SEQ;
  for (int t = 1; t < SEQ; t++){
    if (tg[t] < 0) break;
    float e = logits[((size_t)b*SEQ + t)*NL + j];
    float v[NL]; float mx = -3e38f;
    #pragma unroll
    for (int i = 0; i < NL; i++){
      float ai = __shfl(alpha, i);
      v[i] = ai + tr[i*NL + j];
      mx = fmaxf(mx, v[i]);
    }
    float sum = 0.f;
    #pragma unroll
    for (int i = 0; i < NL; i++) sum += __expf(v[i] - mx);
    float nxt = mx + __logf(sum) + e;
    if (act) alpha = nxt;
  }
  float x = act ? alpha + endv[j] : -3e38f;
  float m2 = x;
  #pragma unroll
  for (int off = 32; off >= 1; off >>= 1) m2 = fmaxf(m2, __shfl_xor(m2, off));
  float se = __expf(x - m2);
  #pragma unroll
  for (int off = 32; off >= 1; off >>= 1) se += __shfl_xor(se, off);
  if (lane == 0) denom[b] = m2 + __logf(se);
}

__global__ void crf_final(const float* __restrict__ numlen, const float* __restrict__ denom,
                          float* __restrict__ out)
{
  if (blockIdx.x == 0 && threadIdx.x == 0){
    float sn = 0.f, sl = 0.f;
    for (int b = 0; b < 16; b++){ sn += numlen[b] - denom[b]; sl += numlen[16+b]; }
    out[0] = -sn / sl;
  }
}

// ---------------------------------------------------------------------------
extern "C" void kernel_launch(void* const* d_in, const int* in_sizes, int n_in,
                              void* d_out, int out_size, void* d_ws, size_t ws_size,
                              hipStream_t stream)
{
  const float* hidden  = (const float*)d_in[0];
  const int*   targets = (const int*)  d_in[1];
  const float* w_ih[4] = {(const float*)d_in[2], (const float*)d_in[6], (const float*)d_in[10], (const float*)d_in[14]};
  const float* w_hh[4] = {(const float*)d_in[3], (const float*)d_in[7], (const float*)d_in[11], (const float*)d_in[15]};
  const float* b_ih[4] = {(const float*)d_in[4], (const float*)d_in[8], (const float*)d_in[12], (const float*)d_in[16]};
  const float* b_hh[4] = {(const float*)d_in[5], (const float*)d_in[9], (const float*)d_in[13], (const float*)d_in[17]};
  const float* clf_w = (const float*)d_in[18];
  const float* clf_b = (const float*)d_in[19];
  const float* trans = (const float*)d_in[20];
  const float* start = (const float*)d_in[21];
  const float* endv  = (const float*)d_in[22];

  // workspace layout (~127 MB)
  char* p = (char*)d_ws;
  auto alloc = [&](size_t bytes){ void* r = (void*)p; p += (bytes + 255) & ~(size_t)255; return r; };
  float* bias   = (float*)alloc((size_t)4*G4*4);
  u16*   xg     = (u16*)  alloc((size_t)2*B*SEQ*G4*2);        // 100.7 MB
  u16*   h1     = (u16*)  alloc((size_t)B*SEQ*2*HD*2);        // 25.2 MB (doubles as th)
  u16*   hgbu   = (u16*)  alloc((size_t)2*2*16*768*2);        // 96 KB h ping-pong [ping][dir][b][k]
  u32*   flags  = (u32*)  alloc((size_t)2*NBLK*4);            // barrier flags
  float* logits = (float*)alloc((size_t)B*SEQ*NL*4);
  float* numlen = (float*)alloc(32*4);
  float* denom  = (float*)alloc(16*4);
  if ((size_t)(p - (char*)d_ws) > ws_size) return;

  BPtrs bp;
  for (int i = 0; i < 4; i++){ bp.bi[i] = b_ih[i]; bp.bh[i] = b_hh[i]; }
  prep_bias<<<48, 256, 0, stream>>>(bp, bias);

  const dim3 ggrid(24, 64);
  const size_t xg_dir = (size_t)B*SEQ*G4;
  const size_t hgb_bytes = (size_t)2*2*16*768*2;
  const size_t flg_bytes = (size_t)2*NBLK*4;

  // ---- layer 0 ----
  gemm_xg_mfma<float><<<ggrid, 256, 0, stream>>>(hidden, HD, w_ih[0], bias + 0*G4, xg);
  gemm_xg_mfma<float><<<ggrid, 256, 0, stream>>>(hidden, HD, w_ih[1], bias + 1*G4, xg + xg_dir);
  hipMemsetAsync(hgbu, 0, hgb_bytes, stream);
  hipMemsetAsync(flags, 0, flg_bytes, stream);
  {
    const u16* a0 = xg; const float* a1 = w_hh[0]; const float* a2 = w_hh[1];
    u16* a3 = hgbu; u32* a4 = flags; u16* a5 = h1;
    void* args[] = { &a0, &a1, &a2, &a3, &a4, &a5 };
    hipLaunchCooperativeKernel(reinterpret_cast<void*>(&scan_kernel<0>),
                               dim3(192), dim3(256), args, 0, stream);
  }

  // ---- layer 1 ----
  gemm_xg_mfma<u16><<<ggrid, 256, 0, stream>>>(h1, 2*HD, w_ih[2], bias + 2*G4, xg);
  gemm_xg_mfma<u16><<<ggrid, 256, 0, stream>>>(h1, 2*HD, w_ih[3], bias + 3*G4, xg + xg_dir);
  hipMemsetAsync(hgbu, 0, hgb_bytes, stream);
  hipMemsetAsync(flags, 0, flg_bytes, stream);
  {
    const u16* a0 = xg; const float* a1 = w_hh[2]; const float* a2 = w_hh[3];
    u16* a3 = hgbu; u32* a4 = flags; u16* a5 = h1;
    void* args[] = { &a0, &a1, &a2, &a3, &a4, &a5 };
    hipLaunchCooperativeKernel(reinterpret_cast<void*>(&scan_kernel<1>),
                               dim3(192), dim3(256), args, 0, stream);
  }

  // ---- classifier + CRF ----
  logits_kernel<<<1024, 256, 0, stream>>>(h1, clf_w, clf_b, logits);
  crf_num<<<16, 256, 0, stream>>>(logits, targets, trans, start, endv, numlen);
  crf_fwd<<<16, 64, 0, stream>>>(logits, targets, trans, start, endv, denom);
  crf_final<<<1, 64, 0, stream>>>(numlen, denom, (float*)d_out);
}